// Round 2
// baseline (715.689 us; speedup 1.0000x reference)
//
#include <hip/hip_runtime.h>
#include <cstddef>

// Problem constants
#define Bc 4
#define Nc 1024
#define Cc 768
#define Hc 12
#define Dc 64
#define QKV_ELEMS ((size_t)Bc * Nc * Cc)   // 3145728

// ---------------------------------------------------------------------------
// K1/K5: out = A[4096x768] @ W[768x768] + bias
// MODE 0: out row-major [4096,768]; MODE 1: head layout [B,H,N,D]
// ---------------------------------------------------------------------------
template <int MODE>
__global__ __launch_bounds__(256) void gemm768_kernel(
    const float* __restrict__ A, const float* __restrict__ W,
    const float* __restrict__ bias, float* __restrict__ out)
{
    __shared__ float As[16][68];  // [k][m]
    __shared__ float Bs[16][68];  // [k][n]
    const int tid = threadIdx.x;
    const int tx = tid & 15, ty = tid >> 4;
    const int m0 = blockIdx.y * 64, n0 = blockIdx.x * 64;

    float acc[4][4] = {};

    for (int kk = 0; kk < 768; kk += 16) {
        {
            const int r  = tid >> 2;
            const int c4 = (tid & 3) << 2;
            const float4 a = *(const float4*)&A[(size_t)(m0 + r) * 768 + kk + c4];
            As[c4 + 0][r] = a.x; As[c4 + 1][r] = a.y;
            As[c4 + 2][r] = a.z; As[c4 + 3][r] = a.w;
        }
        {
            const int r  = tid >> 4;
            const int c4 = (tid & 15) << 2;
            *(float4*)&Bs[r][c4] = *(const float4*)&W[(size_t)(kk + r) * 768 + n0 + c4];
        }
        __syncthreads();
        #pragma unroll
        for (int k = 0; k < 16; ++k) {
            const float4 a = *(const float4*)&As[k][ty * 4];
            const float4 b = *(const float4*)&Bs[k][tx * 4];
            const float av[4] = {a.x, a.y, a.z, a.w};
            const float bv[4] = {b.x, b.y, b.z, b.w};
            #pragma unroll
            for (int i = 0; i < 4; ++i)
                #pragma unroll
                for (int j = 0; j < 4; ++j)
                    acc[i][j] = fmaf(av[i], bv[j], acc[i][j]);
        }
        __syncthreads();
    }

    const int col0 = n0 + tx * 4;
    #pragma unroll
    for (int i = 0; i < 4; ++i) {
        const int m = m0 + ty * 4 + i;
        float4 r;
        r.x = acc[i][0] + bias[col0 + 0];
        r.y = acc[i][1] + bias[col0 + 1];
        r.z = acc[i][2] + bias[col0 + 2];
        r.w = acc[i][3] + bias[col0 + 3];
        if (MODE == 0) {
            *(float4*)&out[(size_t)m * 768 + col0] = r;
        } else {
            const int b = m >> 10, nn = m & 1023;
            const int h = col0 >> 6, d = col0 & 63;
            *(float4*)&out[(((size_t)(b * Hc + h) * Nc + nn) << 6) + d] = r;
        }
    }
}

// ---------------------------------------------------------------------------
// K2: fused scores + online softmax stats.
// Block = (bh, 64-row i-tile). Streams 16 K-tiles of 64 cols.
// Writes raw scores to attn; writes per-row (m, l) to ml.
// LDS tiles are float4 arrays with XOR swizzle: idx = row*16 + (d4 ^ ((row>>2)&7))
// ---------------------------------------------------------------------------
__global__ __launch_bounds__(256) void scores_online_kernel(
    const float* __restrict__ q, const float* __restrict__ k,
    const float* __restrict__ coords,
    const float* __restrict__ Wd1, const float* __restrict__ bd1,
    const float* __restrict__ Wd2, const float* __restrict__ bd2,
    float* __restrict__ attn, float* __restrict__ ml)
{
    __shared__ float4 Qs[64 * 16];
    __shared__ float4 Ks[64 * 16];
    __shared__ float w1[16], b1[16], w2c[16];
    __shared__ float cix[64], ciy[64];
    __shared__ float cjx[64], cjy[64];

    const int tid = threadIdx.x;
    const int bh = blockIdx.y;
    const int b = bh / Hc, h = bh % Hc;
    const int i0 = blockIdx.x * 64;
    const int tx = tid & 15, ty = tid >> 4;

    // Q tile (64 rows x 64 d), swizzled
    {
        const float4* qg = (const float4*)(q + ((size_t)bh * Nc + i0) * Dc);
        #pragma unroll
        for (int l = 0; l < 4; ++l) {
            const int lin = tid + l * 256;
            const int r = lin >> 4, d4 = lin & 15;
            Qs[r * 16 + (d4 ^ ((r >> 2) & 7))] = qg[lin];
        }
    }
    if (tid < 16) {
        w1[tid] = Wd1[tid];
        b1[tid] = bd1[tid];
        w2c[tid] = Wd2[tid * Hc + h];
    }
    if (tid >= 64 && tid < 128) {
        const int t = tid - 64;
        const float2 cc = ((const float2*)coords)[(size_t)b * Nc + i0 + t];
        cix[t] = cc.x; ciy[t] = cc.y;
    }
    const float bd2h = bd2[h];

    float m_r[4] = {-INFINITY, -INFINITY, -INFINITY, -INFINITY};
    float l_r[4] = {0.f, 0.f, 0.f, 0.f};

    const int qsw_base = (4 * ty) * 16;    // rows 4*ty+ii share (row>>2)=ty
    const int tysw = ty & 7;
    const int txsw = tx & 7;

    for (int jt = 0; jt < 16; ++jt) {
        // load K tile + cj coords
        {
            const float4* kg = (const float4*)(k + ((size_t)bh * Nc + jt * 64) * Dc);
            #pragma unroll
            for (int l = 0; l < 4; ++l) {
                const int lin = tid + l * 256;
                const int r = lin >> 4, d4 = lin & 15;
                Ks[r * 16 + (d4 ^ ((r >> 2) & 7))] = kg[lin];
            }
            if (tid < 64) {
                const float2 cc = ((const float2*)coords)[(size_t)b * Nc + jt * 64 + tid];
                cjx[tid] = cc.x; cjy[tid] = cc.y;
            }
        }
        __syncthreads();

        // QK^T 4x4 register tile over d=64
        float acc[4][4] = {};
        #pragma unroll
        for (int d4 = 0; d4 < 16; ++d4) {
            float4 qv[4], kv[4];
            const int qsw = d4 ^ tysw;
            const int ksw = d4 ^ txsw;
            #pragma unroll
            for (int ii = 0; ii < 4; ++ii) qv[ii] = Qs[qsw_base + ii * 16 + qsw];
            #pragma unroll
            for (int jj = 0; jj < 4; ++jj) kv[jj] = Ks[(4 * tx + jj) * 16 + ksw];
            #pragma unroll
            for (int ii = 0; ii < 4; ++ii)
                #pragma unroll
                for (int jj = 0; jj < 4; ++jj) {
                    acc[ii][jj] = fmaf(qv[ii].x, kv[jj].x, acc[ii][jj]);
                    acc[ii][jj] = fmaf(qv[ii].y, kv[jj].y, acc[ii][jj]);
                    acc[ii][jj] = fmaf(qv[ii].z, kv[jj].z, acc[ii][jj]);
                    acc[ii][jj] = fmaf(qv[ii].w, kv[jj].w, acc[ii][jj]);
                }
        }

        // spatial MLP: dist per (ii,jj), then shared-weight t-loop
        float dist[16], sp[16];
        #pragma unroll
        for (int ii = 0; ii < 4; ++ii) {
            const float x0 = cix[4 * ty + ii], y0 = ciy[4 * ty + ii];
            #pragma unroll
            for (int jj = 0; jj < 4; ++jj) {
                const float dx = x0 - cjx[4 * tx + jj];
                const float dy = y0 - cjy[4 * tx + jj];
                dist[ii * 4 + jj] = sqrtf(fmaf(dx, dx, fmaf(dy, dy, 1e-6f)));
                sp[ii * 4 + jj] = bd2h;
            }
        }
        #pragma unroll
        for (int t = 0; t < 16; ++t) {
            const float w = w1[t], bb = b1[t], ww = w2c[t];
            #pragma unroll
            for (int e = 0; e < 16; ++e) {
                const float hb = fmaxf(fmaf(dist[e], w, bb), 0.0f);
                sp[e] = fmaf(hb, ww, sp[e]);
            }
        }

        // combine, write raw scores, online (m,l) update
        #pragma unroll
        for (int ii = 0; ii < 4; ++ii) {
            float s0 = fmaf(acc[ii][0], 0.125f, sp[ii * 4 + 0]);
            float s1 = fmaf(acc[ii][1], 0.125f, sp[ii * 4 + 1]);
            float s2 = fmaf(acc[ii][2], 0.125f, sp[ii * 4 + 2]);
            float s3 = fmaf(acc[ii][3], 0.125f, sp[ii * 4 + 3]);
            const int row = i0 + 4 * ty + ii;
            *(float4*)&attn[((size_t)bh * Nc + row) * Nc + jt * 64 + 4 * tx] =
                make_float4(s0, s1, s2, s3);

            float tmax = fmaxf(fmaxf(s0, s1), fmaxf(s2, s3));
            #pragma unroll
            for (int off = 1; off < 16; off <<= 1)
                tmax = fmaxf(tmax, __shfl_xor(tmax, off));
            const float mnew = fmaxf(m_r[ii], tmax);
            float ts = __expf(s0 - mnew) + __expf(s1 - mnew) +
                       __expf(s2 - mnew) + __expf(s3 - mnew);
            #pragma unroll
            for (int off = 1; off < 16; off <<= 1)
                ts += __shfl_xor(ts, off);
            l_r[ii] = l_r[ii] * __expf(m_r[ii] - mnew) + ts;
            m_r[ii] = mnew;
        }
        __syncthreads();
    }

    if (tx == 0) {
        #pragma unroll
        for (int ii = 0; ii < 4; ++ii) {
            const size_t row = (size_t)bh * Nc + i0 + 4 * ty + ii;
            ml[row * 2 + 0] = m_r[ii];
            ml[row * 2 + 1] = l_r[ii];
        }
    }
}

// ---------------------------------------------------------------------------
// K3: fused normalize + PV.
// Reads raw scores from attn, p = exp(s-m)/l, writes p back to attn (in place,
// block owns its rows), accumulates p @ V into heads [B,N,C].
// ---------------------------------------------------------------------------
__global__ __launch_bounds__(256) void pv_norm_kernel(
    float* __restrict__ attn, const float* __restrict__ v,
    const float* __restrict__ ml, float* __restrict__ heads)
{
    constexpr int AST = 68;
    __shared__ float As[64 * AST];   // p tile [i][j], padded
    __shared__ float Vs[64 * 64];    // v tile [j][d]
    __shared__ float rm[64], ril[64];

    const int tid = threadIdx.x;
    const int bh = blockIdx.y;
    const int b = bh / Hc, h = bh % Hc;
    const int i0 = blockIdx.x * 64;
    const int tx = tid & 15, ty = tid >> 4;

    if (tid < 64) {
        const size_t row = (size_t)bh * Nc + i0 + tid;
        rm[tid] = ml[row * 2 + 0];
        ril[tid] = 1.0f / ml[row * 2 + 1];
    }
    __syncthreads();

    float acc[4][4] = {};

    for (int kk = 0; kk < Nc; kk += 64) {
        const float4* vsrc = (const float4*)(v + ((size_t)bh * Nc + kk) * Dc);
        #pragma unroll
        for (int t = tid; t < 1024; t += 256) {
            const int r = t >> 4, c4 = (t & 15) << 2;
            float* ap = &attn[((size_t)bh * Nc + i0 + r) * Nc + kk + c4];
            float4 s4 = *(const float4*)ap;
            const float mm = rm[r], il = ril[r];
            float4 p;
            p.x = __expf(s4.x - mm) * il;
            p.y = __expf(s4.y - mm) * il;
            p.z = __expf(s4.z - mm) * il;
            p.w = __expf(s4.w - mm) * il;
            *(float4*)ap = p;
            *(float4*)&As[r * AST + c4] = p;
            ((float4*)Vs)[t] = vsrc[t];
        }
        __syncthreads();
        #pragma unroll 8
        for (int jj = 0; jj < 64; ++jj) {
            const float4 bb = *(const float4*)&Vs[jj * 64 + tx * 4];
            #pragma unroll
            for (int ii = 0; ii < 4; ++ii) {
                const float a = As[(ty + (ii << 4)) * AST + jj];
                acc[ii][0] = fmaf(a, bb.x, acc[ii][0]);
                acc[ii][1] = fmaf(a, bb.y, acc[ii][1]);
                acc[ii][2] = fmaf(a, bb.z, acc[ii][2]);
                acc[ii][3] = fmaf(a, bb.w, acc[ii][3]);
            }
        }
        __syncthreads();
    }

    #pragma unroll
    for (int ii = 0; ii < 4; ++ii) {
        const int i = i0 + ty + (ii << 4);
        float4 r4 = make_float4(acc[ii][0], acc[ii][1], acc[ii][2], acc[ii][3]);
        *(float4*)&heads[((size_t)b * Nc + i) * Cc + h * Dc + tx * 4] = r4;
    }
}

// ---------------------------------------------------------------------------
extern "C" void kernel_launch(void* const* d_in, const int* in_sizes, int n_in,
                              void* d_out, int out_size, void* d_ws, size_t ws_size,
                              hipStream_t stream)
{
    (void)in_sizes; (void)n_in; (void)out_size; (void)ws_size;

    const float* x      = (const float*)d_in[0];
    const float* coords = (const float*)d_in[1];
    const float* Wq = (const float*)d_in[2];  const float* bq = (const float*)d_in[3];
    const float* Wk = (const float*)d_in[4];  const float* bk = (const float*)d_in[5];
    const float* Wv = (const float*)d_in[6];  const float* bv = (const float*)d_in[7];
    const float* Wo = (const float*)d_in[8];  const float* bo = (const float*)d_in[9];
    const float* Wd1 = (const float*)d_in[10]; const float* bd1 = (const float*)d_in[11];
    const float* Wd2 = (const float*)d_in[12]; const float* bd2 = (const float*)d_in[13];

    float* out_main = (float*)d_out;            // [B,N,C]
    float* attn     = out_main + QKV_ELEMS;     // [B,H,N,N]

    float* q     = (float*)d_ws;                // [B,H,N,D]
    float* k     = q + QKV_ELEMS;
    float* v     = k + QKV_ELEMS;
    float* heads = v + QKV_ELEMS;               // [B,N,C]
    float* ml    = heads + QKV_ELEMS;           // [B*H*N][2]

    dim3 gGemm(12, 64);
    gemm768_kernel<1><<<gGemm, 256, 0, stream>>>(x, Wq, bq, q);
    gemm768_kernel<1><<<gGemm, 256, 0, stream>>>(x, Wk, bk, k);
    gemm768_kernel<1><<<gGemm, 256, 0, stream>>>(x, Wv, bv, v);

    scores_online_kernel<<<dim3(16, 48), 256, 0, stream>>>(
        q, k, coords, Wd1, bd1, Wd2, bd2, attn, ml);

    pv_norm_kernel<<<dim3(16, 48), 256, 0, stream>>>(attn, v, ml, heads);

    gemm768_kernel<0><<<gGemm, 256, 0, stream>>>(heads, Wo, bo, out_main);
}

// Round 3
// 403.411 us; speedup vs baseline: 1.7741x; 1.7741x over previous
//
#include <hip/hip_runtime.h>
#include <cstddef>
#include <cstdint>

#define Bc 4
#define Nc 1024
#define Cc 768
#define Hc 12
#define Dc 64
#define BHc 48
#define QKV_ELEMS ((size_t)Bc * Nc * Cc)   // 3145728

typedef __attribute__((ext_vector_type(4))) unsigned int u32x4;
typedef __attribute__((ext_vector_type(8))) short s16x8;
typedef __attribute__((ext_vector_type(4))) float fx4;
typedef __attribute__((ext_vector_type(2))) float fx2;

union Frag { u32x4 u; s16x8 s; unsigned short h[8]; };

__device__ inline unsigned short f2bf(float x) {
    union { float f; uint32_t u; } c; c.f = x;
    return (unsigned short)((c.u + 0x7FFFu + ((c.u >> 16) & 1u)) >> 16);
}
__device__ inline float bf2f(unsigned short b) {
    union { uint32_t u; float f; } c; c.u = ((uint32_t)b) << 16;
    return c.f;
}

// ---------------------------------------------------------------------------
// prep_w: Wt_hi/lo[mat][n][k] = split(W[k][n])  (transpose + bf16 hi/lo split)
// ---------------------------------------------------------------------------
__global__ __launch_bounds__(256) void prep_w_kernel(
    const float* __restrict__ Wq, const float* __restrict__ Wk,
    const float* __restrict__ Wv, const float* __restrict__ Wo,
    unsigned short* __restrict__ Thi, unsigned short* __restrict__ Tlo)
{
    __shared__ float scr[64 * 65];
    const int mat = blockIdx.z;
    const float* W = (mat == 0) ? Wq : (mat == 1) ? Wk : (mat == 2) ? Wv : Wo;
    const int k0 = blockIdx.y * 64, n0 = blockIdx.x * 64;
    const int tid = threadIdx.x;

    #pragma unroll
    for (int it = 0; it < 4; ++it) {
        const int lin = tid + it * 256;          // 1024 float4 slots
        const int r = lin >> 4, c4 = (lin & 15) << 2;
        const fx4 v = *(const fx4*)&W[(size_t)(k0 + r) * 768 + n0 + c4];
        scr[r * 65 + c4 + 0] = v[0]; scr[r * 65 + c4 + 1] = v[1];
        scr[r * 65 + c4 + 2] = v[2]; scr[r * 65 + c4 + 3] = v[3];
    }
    __syncthreads();
    unsigned short* th = Thi + (size_t)mat * 768 * 768;
    unsigned short* tl = Tlo + (size_t)mat * 768 * 768;
    #pragma unroll
    for (int it = 0; it < 16; ++it) {
        const int lin = tid + it * 256;          // 4096 elems
        const int n = lin >> 6, kq = lin & 63;
        const float val = scr[kq * 65 + n];
        const size_t o = (size_t)(n0 + n) * 768 + k0 + kq;
        const unsigned short hb = f2bf(val);
        th[o] = hb;
        tl[o] = f2bf(val - bf2f(hb));
    }
}

// ---------------------------------------------------------------------------
// prep_tables: piecewise-linear tables for the distance MLP.
// spatial_h(d) = alpha[idx][h]*d + beta[idx][h], idx = #{t : d > knot_t}
// ---------------------------------------------------------------------------
__global__ __launch_bounds__(256) void prep_tables_kernel(
    const float* __restrict__ Wd1, const float* __restrict__ bd1,
    const float* __restrict__ Wd2, const float* __restrict__ bd2,
    float* __restrict__ knots, float* __restrict__ alphaT, float* __restrict__ betaT)
{
    __shared__ float w1s[16], b1s[16], kn[16];
    __shared__ int rank[16];
    const int tid = threadIdx.x;
    if (tid < 16) {
        const float w1 = Wd1[tid], b1 = bd1[tid];
        w1s[tid] = w1; b1s[tid] = b1;
        kn[tid] = (w1 != 0.0f) ? (-b1 / w1) : INFINITY;
    }
    __syncthreads();
    if (tid < 16) {
        int rk = 0;
        for (int u = 0; u < 16; ++u) {
            const float ku = kn[u], km = kn[tid];
            if (ku < km || (ku == km && u < tid)) ++rk;
        }
        rank[tid] = rk;
        knots[tid] = kn[tid];
    }
    __syncthreads();
    if (tid < 17 * 12) {
        const int s = tid / 12, h = tid % 12;
        float a = 0.0f, be = bd2[h];
        for (int u = 0; u < 16; ++u) {
            const float w1 = w1s[u], b1 = b1s[u];
            bool act;
            if (w1 > 0.0f)      act = (rank[u] < s);
            else if (w1 < 0.0f) act = (rank[u] >= s);
            else                act = (b1 > 0.0f);
            if (act) {
                const float w2 = Wd2[u * 12 + h];
                a  += w2 * w1;
                be += w2 * b1;
            }
        }
        alphaT[s * 12 + h] = a;
        betaT[s * 12 + h]  = be;
    }
}

// ---------------------------------------------------------------------------
// gemm_mfma: out = A[4096x768] @ W[768x768] + bias, bf16x3 via MFMA.
// AMODE 0: A = fp32 (split in-kernel). AMODE 1: A = bf16 hi/lo pair.
// OMODE 0: write bf16 hi/lo pair in head layout [bh][n][d] (q, k)
// OMODE 1: write bf16 hi/lo pair transposed vT [bh][d][n] (v)
// OMODE 2: write fp32 row-major (final out)
// Tile 64x64, BK=64, 4 waves, wave tile 32x32 (2x2 of 16x16 frags).
// LDS is fragment-order: subtile s (rowgrp*2+kc), lane L -> 16B.
// ---------------------------------------------------------------------------
struct SmemG { u32x4 ah[8 * 64]; u32x4 al[8 * 64]; u32x4 bh[8 * 64]; u32x4 bl[8 * 64]; };
struct SmemT { float scr[64 * 65]; };
union SmemU { SmemG g; SmemT t; };

template<int AMODE, int OMODE>
__global__ __launch_bounds__(256) void gemm_mfma_kernel(
    const float* __restrict__ Af,
    const unsigned short* __restrict__ Ahi, const unsigned short* __restrict__ Alo,
    const unsigned short* __restrict__ Bhi, const unsigned short* __restrict__ Blo,
    const float* __restrict__ bias,
    float* __restrict__ outF,
    unsigned short* __restrict__ Ohi, unsigned short* __restrict__ Olo)
{
    __shared__ SmemU sm;
    const int tid = threadIdx.x;
    const int w = tid >> 6, L = tid & 63;
    const int Lr = L & 15, Lg = L >> 4;
    const int m0 = blockIdx.y * 64, n0 = blockIdx.x * 64;

    fx4 acc[2][2] = {};

    for (int kk = 0; kk < 768; kk += 64) {
        if (AMODE == 0) {
            #pragma unroll
            for (int it = 0; it < 2; ++it) {
                const int slot = tid + it * 256;
                const int s = slot >> 6, l = slot & 63;
                const int row = m0 + ((s >> 1) << 4) + (l & 15);
                const int kb = kk + ((s & 1) << 5) + ((l >> 4) << 3);
                const fx4 v0 = *(const fx4*)&Af[(size_t)row * 768 + kb];
                const fx4 v1 = *(const fx4*)&Af[(size_t)row * 768 + kb + 4];
                float vv[8] = {v0[0], v0[1], v0[2], v0[3], v1[0], v1[1], v1[2], v1[3]};
                Frag fh, fl;
                #pragma unroll
                for (int e = 0; e < 8; ++e) {
                    const unsigned short hb = f2bf(vv[e]);
                    fh.h[e] = hb;
                    fl.h[e] = f2bf(vv[e] - bf2f(hb));
                }
                sm.g.ah[slot] = fh.u;
                sm.g.al[slot] = fl.u;
            }
        } else {
            #pragma unroll
            for (int it = 0; it < 2; ++it) {
                const int slot = tid + it * 256;
                const int s = slot >> 6, l = slot & 63;
                const int row = m0 + ((s >> 1) << 4) + (l & 15);
                const int kb = kk + ((s & 1) << 5) + ((l >> 4) << 3);
                sm.g.ah[slot] = *(const u32x4*)&Ahi[(size_t)row * 768 + kb];
                sm.g.al[slot] = *(const u32x4*)&Alo[(size_t)row * 768 + kb];
            }
        }
        #pragma unroll
        for (int it = 0; it < 2; ++it) {
            const int slot = tid + it * 256;
            const int s = slot >> 6, l = slot & 63;
            const int col = n0 + ((s >> 1) << 4) + (l & 15);
            const int kb = kk + ((s & 1) << 5) + ((l >> 4) << 3);
            sm.g.bh[slot] = *(const u32x4*)&Bhi[(size_t)col * 768 + kb];
            sm.g.bl[slot] = *(const u32x4*)&Blo[(size_t)col * 768 + kb];
        }
        __syncthreads();
        #pragma unroll
        for (int kc = 0; kc < 2; ++kc) {
            Frag ah[2], al[2], bh[2], bl[2];
            #pragma unroll
            for (int mm = 0; mm < 2; ++mm) {
                const int rg = (w >> 1) * 2 + mm;
                ah[mm].u = sm.g.ah[(rg * 2 + kc) * 64 + L];
                al[mm].u = sm.g.al[(rg * 2 + kc) * 64 + L];
            }
            #pragma unroll
            for (int nn = 0; nn < 2; ++nn) {
                const int cg = (w & 1) * 2 + nn;
                bh[nn].u = sm.g.bh[(cg * 2 + kc) * 64 + L];
                bl[nn].u = sm.g.bl[(cg * 2 + kc) * 64 + L];
            }
            #pragma unroll
            for (int mm = 0; mm < 2; ++mm)
                #pragma unroll
                for (int nn = 0; nn < 2; ++nn) {
                    acc[mm][nn] = __builtin_amdgcn_mfma_f32_16x16x32_bf16(ah[mm].s, bh[nn].s, acc[mm][nn], 0, 0, 0);
                    acc[mm][nn] = __builtin_amdgcn_mfma_f32_16x16x32_bf16(ah[mm].s, bl[nn].s, acc[mm][nn], 0, 0, 0);
                    acc[mm][nn] = __builtin_amdgcn_mfma_f32_16x16x32_bf16(al[mm].s, bh[nn].s, acc[mm][nn], 0, 0, 0);
                }
        }
        __syncthreads();
    }

    if (OMODE == 0 || OMODE == 2) {
        #pragma unroll
        for (int mm = 0; mm < 2; ++mm) {
            const int row = m0 + (w >> 1) * 32 + mm * 16 + Lg * 4;
            #pragma unroll
            for (int nn = 0; nn < 2; ++nn) {
                const int col = n0 + (w & 1) * 32 + nn * 16 + Lr;
                const float bs = bias[col];
                #pragma unroll
                for (int r = 0; r < 4; ++r) {
                    const float val = acc[mm][nn][r] + bs;
                    if (OMODE == 2) {
                        outF[(size_t)(row + r) * 768 + col] = val;
                    } else {
                        const int b = (row + r) >> 10, nloc = (row + r) & 1023;
                        const int h = col >> 6, d = col & 63;
                        const size_t o = (((size_t)(b * Hc + h) * Nc + nloc) << 6) + d;
                        const unsigned short hb = f2bf(val);
                        Ohi[o] = hb;
                        Olo[o] = f2bf(val - bf2f(hb));
                    }
                }
            }
        }
    } else {
        // OMODE 1: transpose within block via LDS, write vT[bh][d][n]
        #pragma unroll
        for (int mm = 0; mm < 2; ++mm) {
            const int rl = (w >> 1) * 32 + mm * 16 + Lg * 4;
            #pragma unroll
            for (int nn = 0; nn < 2; ++nn) {
                const int cl = (w & 1) * 32 + nn * 16 + Lr;
                const float bs = bias[n0 + cl];
                #pragma unroll
                for (int r = 0; r < 4; ++r)
                    sm.t.scr[(rl + r) * 65 + cl] = acc[mm][nn][r] + bs;
            }
        }
        __syncthreads();
        const int b = m0 >> 10, h = n0 >> 6, nbase = m0 & 1023;
        #pragma unroll
        for (int it = 0; it < 16; ++it) {
            const int lin = tid + it * 256;
            const int dd = lin >> 6, j = lin & 63;
            const float val = sm.t.scr[j * 65 + dd];
            const size_t o = (size_t)((b * Hc + h) * Dc + dd) * Nc + nbase + j;
            const unsigned short hb = f2bf(val);
            Ohi[o] = hb;
            Olo[o] = f2bf(val - bf2f(hb));
        }
    }
}

// ---------------------------------------------------------------------------
// scores_mfma: raw scores (QK^T*scale + PL-MLP(dist)) -> attn; online (m,l) -> ml
// Block = (i-tile 64, bh). 4 waves, wave = 16 rows. MFMA bf16x3.
// ---------------------------------------------------------------------------
__global__ __launch_bounds__(256) void scores_mfma_kernel(
    const unsigned short* __restrict__ qhi, const unsigned short* __restrict__ qlo,
    const unsigned short* __restrict__ khi, const unsigned short* __restrict__ klo,
    const float* __restrict__ coords,
    const float* __restrict__ knots_g, const float* __restrict__ alphaT,
    const float* __restrict__ betaT,
    float* __restrict__ attn, float* __restrict__ ml)
{
    __shared__ u32x4 KsH[8 * 64], KsL[8 * 64];
    __shared__ float cjx[64], cjy[64];
    __shared__ float aH[17], bH[17];

    const int tid = threadIdx.x;
    const int w = tid >> 6, L = tid & 63;
    const int Lr = L & 15, Lg = L >> 4;
    const int bh = blockIdx.y, b = bh / Hc, h = bh % Hc;
    const int i0 = blockIdx.x * 64;
    const int wrow = i0 + w * 16;

    if (tid < 17) { aH[tid] = alphaT[tid * 12 + h]; bH[tid] = betaT[tid * 12 + h]; }
    float kn[16];
    #pragma unroll
    for (int t = 0; t < 16; ++t) kn[t] = knots_g[t];

    Frag qh[2], ql[2];
    #pragma unroll
    for (int kc = 0; kc < 2; ++kc) {
        const size_t o = ((size_t)bh * Nc + wrow + Lr) * 64 + kc * 32 + Lg * 8;
        qh[kc].u = *(const u32x4*)&qhi[o];
        ql[kc].u = *(const u32x4*)&qlo[o];
    }
    float cix4[4], ciy4[4];
    #pragma unroll
    for (int r = 0; r < 4; ++r) {
        const fx2 cc = *(const fx2*)&coords[((size_t)b * Nc + wrow + Lg * 4 + r) * 2];
        cix4[r] = cc[0]; ciy4[r] = cc[1];
    }

    float m_r[4] = {-INFINITY, -INFINITY, -INFINITY, -INFINITY};
    float l_r[4] = {0.f, 0.f, 0.f, 0.f};

    for (int jt = 0; jt < 16; ++jt) {
        #pragma unroll
        for (int it = 0; it < 2; ++it) {
            const int slot = tid + it * 256;
            const int s = slot >> 6, l = slot & 63;
            const int jrow = jt * 64 + ((s >> 1) << 4) + (l & 15);
            const int kb = ((s & 1) << 5) + ((l >> 4) << 3);
            const size_t o = ((size_t)bh * Nc + jrow) * 64 + kb;
            KsH[slot] = *(const u32x4*)&khi[o];
            KsL[slot] = *(const u32x4*)&klo[o];
        }
        if (tid < 64) {
            const fx2 cc = *(const fx2*)&coords[((size_t)b * Nc + jt * 64 + tid) * 2];
            cjx[tid] = cc[0]; cjy[tid] = cc[1];
        }
        __syncthreads();

        fx4 acc[4] = {};
        #pragma unroll
        for (int kc = 0; kc < 2; ++kc) {
            #pragma unroll
            for (int cg = 0; cg < 4; ++cg) {
                Frag kbh, kbl;
                kbh.u = KsH[(cg * 2 + kc) * 64 + L];
                kbl.u = KsL[(cg * 2 + kc) * 64 + L];
                acc[cg] = __builtin_amdgcn_mfma_f32_16x16x32_bf16(qh[kc].s, kbh.s, acc[cg], 0, 0, 0);
                acc[cg] = __builtin_amdgcn_mfma_f32_16x16x32_bf16(qh[kc].s, kbl.s, acc[cg], 0, 0, 0);
                acc[cg] = __builtin_amdgcn_mfma_f32_16x16x32_bf16(ql[kc].s, kbh.s, acc[cg], 0, 0, 0);
            }
        }

        float sv[4][4];
        #pragma unroll
        for (int cg = 0; cg < 4; ++cg) {
            const int jl = cg * 16 + Lr;
            const float cx = cjx[jl], cy = cjy[jl];
            #pragma unroll
            for (int r = 0; r < 4; ++r) {
                const float dx = cix4[r] - cx, dy = ciy4[r] - cy;
                const float dist = sqrtf(fmaf(dx, dx, fmaf(dy, dy, 1e-6f)));
                int idx = 0;
                #pragma unroll
                for (int t = 0; t < 16; ++t) idx += (dist > kn[t]) ? 1 : 0;
                const float sp = fmaf(aH[idx], dist, bH[idx]);
                sv[cg][r] = fmaf(acc[cg][r], 0.125f, sp);
            }
        }
        #pragma unroll
        for (int r = 0; r < 4; ++r) {
            const int row = wrow + Lg * 4 + r;
            #pragma unroll
            for (int cg = 0; cg < 4; ++cg)
                attn[((size_t)bh * Nc + row) * Nc + jt * 64 + cg * 16 + Lr] = sv[cg][r];
        }
        #pragma unroll
        for (int r = 0; r < 4; ++r) {
            float tm = fmaxf(fmaxf(sv[0][r], sv[1][r]), fmaxf(sv[2][r], sv[3][r]));
            #pragma unroll
            for (int off = 1; off < 16; off <<= 1)
                tm = fmaxf(tm, __shfl_xor(tm, off));
            const float mnew = fmaxf(m_r[r], tm);
            float ts = __expf(sv[0][r] - mnew) + __expf(sv[1][r] - mnew)
                     + __expf(sv[2][r] - mnew) + __expf(sv[3][r] - mnew);
            #pragma unroll
            for (int off = 1; off < 16; off <<= 1)
                ts += __shfl_xor(ts, off);
            l_r[r] = l_r[r] * __expf(m_r[r] - mnew) + ts;
            m_r[r] = mnew;
        }
        __syncthreads();
    }

    if (Lr == 0) {
        #pragma unroll
        for (int r = 0; r < 4; ++r) {
            const size_t row = (size_t)bh * Nc + wrow + Lg * 4 + r;
            ml[row * 2 + 0] = m_r[r];
            ml[row * 2 + 1] = l_r[r];
        }
    }
}

// ---------------------------------------------------------------------------
// pv_mfma: p = exp(s-m)/l (writes p to attn in place), heads = p @ V via bf16x3
// ---------------------------------------------------------------------------
__global__ __launch_bounds__(256) void pv_mfma_kernel(
    float* __restrict__ attn,
    const unsigned short* __restrict__ vThi, const unsigned short* __restrict__ vTlo,
    const float* __restrict__ ml,
    unsigned short* __restrict__ Hhi, unsigned short* __restrict__ Hlo)
{
    __shared__ u32x4 VsH[8 * 64], VsL[8 * 64];
    const int tid = threadIdx.x;
    const int w = tid >> 6, L = tid & 63;
    const int Lr = L & 15, Lg = L >> 4;
    const int bh = blockIdx.y, b = bh / Hc, h = bh % Hc;
    const int i0 = blockIdx.x * 64;
    const int wrow = i0 + w * 16;

    const size_t prow = (size_t)bh * Nc + wrow + Lr;
    const float mrow = ml[prow * 2 + 0];
    const float il = 1.0f / ml[prow * 2 + 1];

    fx4 acc[4] = {};

    for (int jt = 0; jt < 16; ++jt) {
        #pragma unroll
        for (int it = 0; it < 2; ++it) {
            const int slot = tid + it * 256;
            const int s = slot >> 6, l = slot & 63;
            const int dd = ((s >> 1) << 4) + (l & 15);
            const int jb = jt * 64 + ((s & 1) << 5) + ((l >> 4) << 3);
            const size_t o = ((size_t)bh * Dc + dd) * Nc + jb;
            VsH[slot] = *(const u32x4*)&vThi[o];
            VsL[slot] = *(const u32x4*)&vTlo[o];
        }
        __syncthreads();

        #pragma unroll
        for (int kc = 0; kc < 2; ++kc) {
            float* ap = &attn[prow * Nc + jt * 64 + kc * 32 + Lg * 8];
            const fx4 s0 = *(const fx4*)ap;
            const fx4 s1 = *(const fx4*)(ap + 4);
            float p[8];
            p[0] = __expf(s0[0] - mrow) * il; p[1] = __expf(s0[1] - mrow) * il;
            p[2] = __expf(s0[2] - mrow) * il; p[3] = __expf(s0[3] - mrow) * il;
            p[4] = __expf(s1[0] - mrow) * il; p[5] = __expf(s1[1] - mrow) * il;
            p[6] = __expf(s1[2] - mrow) * il; p[7] = __expf(s1[3] - mrow) * il;
            fx4 w0, w1;
            w0[0] = p[0]; w0[1] = p[1]; w0[2] = p[2]; w0[3] = p[3];
            w1[0] = p[4]; w1[1] = p[5]; w1[2] = p[6]; w1[3] = p[7];
            *(fx4*)ap = w0;
            *(fx4*)(ap + 4) = w1;
            Frag ph, pl;
            #pragma unroll
            for (int e = 0; e < 8; ++e) {
                const unsigned short hb = f2bf(p[e]);
                ph.h[e] = hb;
                pl.h[e] = f2bf(p[e] - bf2f(hb));
            }
            #pragma unroll
            for (int dg = 0; dg < 4; ++dg) {
                Frag vh, vl;
                vh.u = VsH[(dg * 2 + kc) * 64 + L];
                vl.u = VsL[(dg * 2 + kc) * 64 + L];
                acc[dg] = __builtin_amdgcn_mfma_f32_16x16x32_bf16(ph.s, vh.s, acc[dg], 0, 0, 0);
                acc[dg] = __builtin_amdgcn_mfma_f32_16x16x32_bf16(ph.s, vl.s, acc[dg], 0, 0, 0);
                acc[dg] = __builtin_amdgcn_mfma_f32_16x16x32_bf16(pl.s, vh.s, acc[dg], 0, 0, 0);
            }
        }
        __syncthreads();
    }

    #pragma unroll
    for (int dg = 0; dg < 4; ++dg) {
        #pragma unroll
        for (int r = 0; r < 4; ++r) {
            const int i = wrow + Lg * 4 + r;
            const int col = h * 64 + dg * 16 + Lr;
            const float val = acc[dg][r];
            const size_t o = (size_t)(b * Nc + i) * Cc + col;
            const unsigned short hb = f2bf(val);
            Hhi[o] = hb;
            Hlo[o] = f2bf(val - bf2f(hb));
        }
    }
}

// ---------------------------------------------------------------------------
extern "C" void kernel_launch(void* const* d_in, const int* in_sizes, int n_in,
                              void* d_out, int out_size, void* d_ws, size_t ws_size,
                              hipStream_t stream)
{
    (void)in_sizes; (void)n_in; (void)out_size; (void)ws_size;

    const float* x      = (const float*)d_in[0];
    const float* coords = (const float*)d_in[1];
    const float* Wq = (const float*)d_in[2];  const float* bq = (const float*)d_in[3];
    const float* Wk = (const float*)d_in[4];  const float* bk = (const float*)d_in[5];
    const float* Wv = (const float*)d_in[6];  const float* bv = (const float*)d_in[7];
    const float* Wo = (const float*)d_in[8];  const float* bo = (const float*)d_in[9];
    const float* Wd1 = (const float*)d_in[10]; const float* bd1 = (const float*)d_in[11];
    const float* Wd2 = (const float*)d_in[12]; const float* bd2 = (const float*)d_in[13];

    float* out_main = (float*)d_out;            // [B,N,C]
    float* attn     = out_main + QKV_ELEMS;     // [B,H,N,N]

    uint8_t* wsb = (uint8_t*)d_ws;
    const size_t SZ_BF = (size_t)BHc * Nc * Dc * 2;     // 6291456 B
    const size_t SZ_W  = (size_t)768 * 768 * 2;         // 1179648 B per mat
    unsigned short* qhi  = (unsigned short*)(wsb + 0 * SZ_BF);  // later: heads_hi
    unsigned short* qlo  = (unsigned short*)(wsb + 1 * SZ_BF);  // later: heads_lo
    unsigned short* khi  = (unsigned short*)(wsb + 2 * SZ_BF);
    unsigned short* klo  = (unsigned short*)(wsb + 3 * SZ_BF);
    unsigned short* vThi = (unsigned short*)(wsb + 4 * SZ_BF);
    unsigned short* vTlo = (unsigned short*)(wsb + 5 * SZ_BF);
    unsigned short* Thi  = (unsigned short*)(wsb + 6 * SZ_BF);
    unsigned short* Tlo  = (unsigned short*)(wsb + 6 * SZ_BF + 4 * SZ_W);
    float* mlp    = (float*)(wsb + 6 * SZ_BF + 8 * SZ_W);       // [BH*N][2]
    float* knots  = mlp + (size_t)BHc * Nc * 2;
    float* alphaT = knots + 16;
    float* betaT  = alphaT + 17 * 12;

    prep_w_kernel<<<dim3(12, 12, 4), 256, 0, stream>>>(Wq, Wk, Wv, Wo, Thi, Tlo);
    prep_tables_kernel<<<1, 256, 0, stream>>>(Wd1, bd1, Wd2, bd2, knots, alphaT, betaT);

    dim3 gGemm(12, 64);
    gemm_mfma_kernel<0, 0><<<gGemm, 256, 0, stream>>>(
        x, nullptr, nullptr, Thi + 0 * 768 * 768, Tlo + 0 * 768 * 768, bq,
        nullptr, qhi, qlo);
    gemm_mfma_kernel<0, 0><<<gGemm, 256, 0, stream>>>(
        x, nullptr, nullptr, Thi + 1 * 768 * 768, Tlo + 1 * 768 * 768, bk,
        nullptr, khi, klo);
    gemm_mfma_kernel<0, 1><<<gGemm, 256, 0, stream>>>(
        x, nullptr, nullptr, Thi + 2 * 768 * 768, Tlo + 2 * 768 * 768, bv,
        nullptr, vThi, vTlo);

    scores_mfma_kernel<<<dim3(16, 48), 256, 0, stream>>>(
        qhi, qlo, khi, klo, coords, knots, alphaT, betaT, attn, mlp);

    pv_mfma_kernel<<<dim3(16, 48), 256, 0, stream>>>(
        attn, vThi, vTlo, mlp, qhi, qlo);

    gemm_mfma_kernel<1, 2><<<gGemm, 256, 0, stream>>>(
        nullptr, qhi, qlo, Thi + 3 * 768 * 768, Tlo + 3 * 768 * 768, bo,
        out_main, nullptr, nullptr);
}